// Round 4
// baseline (142.563 us; speedup 1.0000x reference)
//
#include <hip/hip_runtime.h>
#include <hip/hip_fp16.h>

// BasisFunction2D, round 14: FUSE precompute into bf2d (kill one launch).
// R13 post-mortem: half2 math was neutral (compute phase ~4 us of a ~29 us
// kernel budget; fills ~94 us untouchable). Remaining addressable cost is
// the serial precompute dispatch (~4-5 us: launch gap + 2-3 us run) and the
// zc reload traffic in the compute loop. This round:
//  - tables (32 z + 2 x grid_coord evals/thread) computed IN-KERNEL into
//    registers, after a depth-1 prefetch of stage iter-0 (32 KB/CU of P in
//    flight) so table math hides under HBM latency. No fences, no spins.
//  - ztab packed 1 dword/j: (idx*CSTRIDE)<<16 | fp16(wz); compute j-loop
//    fully unrolled so ztab stays in VGPRs (rule #20).
//  - out zeroing via hipMemsetAsync (capturable memset node).
//  - stage loop + compute math byte-identical to R13 (proven R10 shape,
//    512-B stripes, CSTRIDE 133, 153.7 KB LDS, 1 block/CU, grid 256).
// Predict: dur 125.3 -> ~120-122, FETCH ~76 MB on fused kernel, absmax
// exactly 0.0009765625 (same math as R13).

#define NG        16
#define NB        17              // NG+1
#define IN_X      32
#define IN_Z      32
#define OUT_DIM   64
#define BATCH     512
#define CELLS     (NB * NB)       // 289
#define CSTRIDE   133             // 4*33 + 1: odd cell stride (bank spread)
#define ILSTRIDE  33              // per-i row stride inside a cell
#define XSTR_A    (NB * CSTRIDE)  // 2261: gx -> +17 cells
#define STASKS    (CELLS * 32)    // 9248 float4-pair staging tasks

typedef __fp16 h2v __attribute__((ext_vector_type(2)));

// pack two floats as fp16 pair (v_cvt_pkrtz, 1 instr): lo = a, hi = b
__device__ __forceinline__ unsigned pack_h2(float a, float b) {
    h2v v = __builtin_amdgcn_cvt_pkrtz(a, b);
    return __builtin_bit_cast(unsigned, v);
}
__device__ __forceinline__ __half2 u2h(unsigned u) {
    return __builtin_bit_cast(__half2, u);
}

__device__ __forceinline__ void grid_coord(float v,
                                           const float* __restrict__ borders,
                                           const float* __restrict__ inv_len,
                                           int& idx, float& w) {
    float e   = expf(-fabsf(v));
    float cdf = (v > 0.f) ? (1.f - 0.5f * e) : (0.5f * e);
    int t = (int)(cdf * 16.f);
    t = t < 0 ? 0 : (t > NG - 1 ? NG - 1 : t);
    idx = t;
    w = (v - borders[t]) * inv_len[t];
}

__global__ __launch_bounds__(1024, 1)
void bf2d_fused(const float* __restrict__ x,
                const float* __restrict__ z,
                const float* __restrict__ borders,
                const float* __restrict__ inv_len,
                const float* __restrict__ P,
                float* __restrict__ out) {
    // lds[cell*133 + il*33 + j] = half2 (P[cell,o0,i,j], P[cell,o1,i,j])
    __shared__ unsigned lds[CELLS * CSTRIDE];   // 38437 dwords = 153748 B

    const int tid = threadIdx.x;                // 1024 threads
    const int op  = blockIdx.x & 31;            // o-pair
    const int iq  = blockIdx.x >> 5;            // i-quad 0..7
    const int o0  = op * 2;
    const int b   = tid & (BATCH - 1);
    const int ih  = tid >> 9;                   // 0 or 1
    const int il0 = 2 * ih, il1 = 2 * ih + 1;

    // P float index: cell*65536 + o*1024 + i*32 + j
    const float* Pb = P + (size_t)o0 * 1024 + iq * 128;

    // ---- depth-1 prefetch of stage iter 0 (tid < 1024 < STASKS always) ----
    float4 a0v, b0v;
    {
        const int c = tid >> 5, f4 = tid & 31;
        const float* g = Pb + (size_t)c * 65536 + f4 * 4;
        a0v = *(const float4*)g;                // o0 stripe, 512-B bursts
        b0v = *(const float4*)(g + 1024);       // o1 stripe
    }

    // ---- per-thread tables in registers; math hides under P loads ----
    // ztab[j] = (idx_z*CSTRIDE)<<16 | fp16(wz)
    unsigned ztab[IN_Z];
    #pragma unroll
    for (int j = 0; j < IN_Z; ++j) {
        int idx; float w;
        grid_coord(z[j * BATCH + b], borders, inv_len, idx, w);
        ztab[j] = ((unsigned)(idx * CSTRIDE) << 16)
                | (pack_h2(w, 0.f) & 0xFFFFu);
    }
    int xi0, xi1; float xw0f, xw1f;
    grid_coord(x[(iq * 4 + il0) * BATCH + b], borders, inv_len, xi0, xw0f);
    grid_coord(x[(iq * 4 + il1) * BATCH + b], borders, inv_len, xi1, xw1f);
    const __half2 wx0 = u2h(pack_h2(xw0f, xw0f));
    const __half2 wx1 = u2h(pack_h2(xw1f, xw1f));
    const int xo0 = xi0 * XSTR_A + il0 * ILSTRIDE;
    const int xo1 = xi1 * XSTR_A + il1 * ILSTRIDE;

    // ---- stage iter 0 (loads already in flight) ----
    {
        const int c = tid >> 5, f4 = tid & 31;
        unsigned* d = &lds[c * CSTRIDE + (f4 >> 3) * ILSTRIDE
                           + ((f4 & 7) << 2)];
        d[0] = pack_h2(a0v.x, b0v.x);
        d[1] = pack_h2(a0v.y, b0v.y);
        d[2] = pack_h2(a0v.z, b0v.z);
        d[3] = pack_h2(a0v.w, b0v.w);
    }
    // ---- stage iters 1..9, proven R10 shape (compiler pipelines) ----
    #pragma unroll
    for (int it = 1; it < 10; ++it) {
        const int k = tid + it * 1024;
        if (k < STASKS) {
            const int c  = k >> 5;
            const int f4 = k & 31;              // il = f4>>3, j4 = (f4&7)*4
            const float* g = Pb + (size_t)c * 65536 + f4 * 4;
            const float4 a = *(const float4*)g;           // o0 stripe
            const float4 bb = *(const float4*)(g + 1024); // o1 stripe
            unsigned* d = &lds[c * CSTRIDE + (f4 >> 3) * ILSTRIDE
                               + ((f4 & 7) << 2)];
            d[0] = pack_h2(a.x, bb.x);
            d[1] = pack_h2(a.y, bb.y);
            d[2] = pack_h2(a.z, bb.z);
            d[3] = pack_h2(a.w, bb.w);
        }
    }
    __syncthreads();

    // ---- compute: j fully unrolled, tables from VGPRs ----
    __half2 acc0 = __float2half2_rn(0.f);       // il0 accumulator (o0,o1)
    __half2 acc1 = __float2half2_rn(0.f);       // il1 accumulator
    #pragma unroll
    for (int j = 0; j < IN_Z; ++j) {
        const unsigned u  = ztab[j];
        const unsigned lo = u & 0xFFFFu;
        const __half2 wz  = u2h(lo | (lo << 16));
        const int     zo  = (int)(u >> 16) + j;
        {
            const int base = xo0 + zo;
            const __half2 q0 = u2h(lds[base]);
            const __half2 q1 = u2h(lds[base + CSTRIDE]);          // read2
            const __half2 v0 = u2h(lds[base + XSTR_A]);
            const __half2 v1 = u2h(lds[base + XSTR_A + CSTRIDE]); // read2
            const __half2 zlo = __hfma2(wz, __hsub2(q1, q0), q0);
            const __half2 zhi = __hfma2(wz, __hsub2(v1, v0), v0);
            acc0 = __hadd2(acc0, __hfma2(wx0, __hsub2(zhi, zlo), zlo));
        }
        {
            const int base = xo1 + zo;
            const __half2 q0 = u2h(lds[base]);
            const __half2 q1 = u2h(lds[base + CSTRIDE]);
            const __half2 v0 = u2h(lds[base + XSTR_A]);
            const __half2 v1 = u2h(lds[base + XSTR_A + CSTRIDE]);
            const __half2 zlo = __hfma2(wz, __hsub2(q1, q0), q0);
            const __half2 zhi = __hfma2(wz, __hsub2(v1, v0), v0);
            acc1 = __hadd2(acc1, __hfma2(wx1, __hsub2(zhi, zlo), zlo));
        }
    }

    // f32 combine of the two per-il half2 partial sums
    const float accx = __low2float(acc0)  + __low2float(acc1);
    const float accy = __high2float(acc0) + __high2float(acc1);

    atomicAdd(&out[o0 * BATCH + b],       accx);
    atomicAdd(&out[(o0 + 1) * BATCH + b], accy);
}

extern "C" void kernel_launch(void* const* d_in, const int* in_sizes, int n_in,
                              void* d_out, int out_size, void* d_ws, size_t ws_size,
                              hipStream_t stream) {
    const float* x       = (const float*)d_in[0];   // (32, 512)
    const float* z       = (const float*)d_in[1];   // (32, 512)
    const float* P       = (const float*)d_in[2];   // (17,17,64,32,32)
    const float* borders = (const float*)d_in[3];   // (17,)
    const float* inv_len = (const float*)d_in[4];   // (16,)
    float* out = (float*)d_out;                     // (64, 512) = 32768

    hipMemsetAsync(out, 0, OUT_DIM * BATCH * sizeof(float), stream);
    bf2d_fused<<<dim3(32 * 8), dim3(1024), 0, stream>>>(
        x, z, borders, inv_len, P, out);
}

// Round 5
// 141.508 us; speedup vs baseline: 1.0075x; 1.0075x over previous
//
#include <hip/hip_runtime.h>
#include <hip/hip_fp16.h>

// BasisFunction2D, round 15: R14 fusion with the REGISTER BUDGET fixed.
// R14 post-mortem (counters): VGPR_Count=64, WRITE_SIZE=22.6 MB of scratch,
// warm replays 49 us @ 464 GB/s -> compiler spilled ztab[32] (default
// heuristic targets 8 waves/EU = 64 VGPR; my (1024,1) bound didn't raise
// the cap). Fix: __launch_bounds__(1024, 4) -- 1024 thr = 16 waves = 4/EU,
// VGPR cap 512/4 = 128; live state ~100 VGPRs fits. NOTHING else changed.
// Predict: VGPR ~100-120, WRITE 22.6 MB -> ~150 KB, kernel 49 -> 15-18 us,
// dur 142.6 -> ~117-121, absmax exactly 0.0009765625.

#define NG        16
#define NB        17              // NG+1
#define IN_X      32
#define IN_Z      32
#define OUT_DIM   64
#define BATCH     512
#define CELLS     (NB * NB)       // 289
#define CSTRIDE   133             // 4*33 + 1: odd cell stride (bank spread)
#define ILSTRIDE  33              // per-i row stride inside a cell
#define XSTR_A    (NB * CSTRIDE)  // 2261: gx -> +17 cells
#define STASKS    (CELLS * 32)    // 9248 float4-pair staging tasks

typedef __fp16 h2v __attribute__((ext_vector_type(2)));

// pack two floats as fp16 pair (v_cvt_pkrtz, 1 instr): lo = a, hi = b
__device__ __forceinline__ unsigned pack_h2(float a, float b) {
    h2v v = __builtin_amdgcn_cvt_pkrtz(a, b);
    return __builtin_bit_cast(unsigned, v);
}
__device__ __forceinline__ __half2 u2h(unsigned u) {
    return __builtin_bit_cast(__half2, u);
}

__device__ __forceinline__ void grid_coord(float v,
                                           const float* __restrict__ borders,
                                           const float* __restrict__ inv_len,
                                           int& idx, float& w) {
    float e   = expf(-fabsf(v));
    float cdf = (v > 0.f) ? (1.f - 0.5f * e) : (0.5f * e);
    int t = (int)(cdf * 16.f);
    t = t < 0 ? 0 : (t > NG - 1 ? NG - 1 : t);
    idx = t;
    w = (v - borders[t]) * inv_len[t];
}

__global__ __launch_bounds__(1024, 4)
void bf2d_fused(const float* __restrict__ x,
                const float* __restrict__ z,
                const float* __restrict__ borders,
                const float* __restrict__ inv_len,
                const float* __restrict__ P,
                float* __restrict__ out) {
    // lds[cell*133 + il*33 + j] = half2 (P[cell,o0,i,j], P[cell,o1,i,j])
    __shared__ unsigned lds[CELLS * CSTRIDE];   // 38437 dwords = 153748 B

    const int tid = threadIdx.x;                // 1024 threads
    const int op  = blockIdx.x & 31;            // o-pair
    const int iq  = blockIdx.x >> 5;            // i-quad 0..7
    const int o0  = op * 2;
    const int b   = tid & (BATCH - 1);
    const int ih  = tid >> 9;                   // 0 or 1
    const int il0 = 2 * ih, il1 = 2 * ih + 1;

    // P float index: cell*65536 + o*1024 + i*32 + j
    const float* Pb = P + (size_t)o0 * 1024 + iq * 128;

    // ---- depth-1 prefetch of stage iter 0 (tid < 1024 < STASKS always) ----
    float4 a0v, b0v;
    {
        const int c = tid >> 5, f4 = tid & 31;
        const float* g = Pb + (size_t)c * 65536 + f4 * 4;
        a0v = *(const float4*)g;                // o0 stripe, 512-B bursts
        b0v = *(const float4*)(g + 1024);       // o1 stripe
    }

    // ---- per-thread tables in registers; math hides under P loads ----
    // ztab[j] = (idx_z*CSTRIDE)<<16 | fp16(wz)
    unsigned ztab[IN_Z];
    #pragma unroll
    for (int j = 0; j < IN_Z; ++j) {
        int idx; float w;
        grid_coord(z[j * BATCH + b], borders, inv_len, idx, w);
        ztab[j] = ((unsigned)(idx * CSTRIDE) << 16)
                | (pack_h2(w, 0.f) & 0xFFFFu);
    }
    int xi0, xi1; float xw0f, xw1f;
    grid_coord(x[(iq * 4 + il0) * BATCH + b], borders, inv_len, xi0, xw0f);
    grid_coord(x[(iq * 4 + il1) * BATCH + b], borders, inv_len, xi1, xw1f);
    const __half2 wx0 = u2h(pack_h2(xw0f, xw0f));
    const __half2 wx1 = u2h(pack_h2(xw1f, xw1f));
    const int xo0 = xi0 * XSTR_A + il0 * ILSTRIDE;
    const int xo1 = xi1 * XSTR_A + il1 * ILSTRIDE;

    // ---- stage iter 0 (loads already in flight) ----
    {
        const int c = tid >> 5, f4 = tid & 31;
        unsigned* d = &lds[c * CSTRIDE + (f4 >> 3) * ILSTRIDE
                           + ((f4 & 7) << 2)];
        d[0] = pack_h2(a0v.x, b0v.x);
        d[1] = pack_h2(a0v.y, b0v.y);
        d[2] = pack_h2(a0v.z, b0v.z);
        d[3] = pack_h2(a0v.w, b0v.w);
    }
    // ---- stage iters 1..9, proven R10 shape (compiler pipelines) ----
    #pragma unroll
    for (int it = 1; it < 10; ++it) {
        const int k = tid + it * 1024;
        if (k < STASKS) {
            const int c  = k >> 5;
            const int f4 = k & 31;              // il = f4>>3, j4 = (f4&7)*4
            const float* g = Pb + (size_t)c * 65536 + f4 * 4;
            const float4 a = *(const float4*)g;           // o0 stripe
            const float4 bb = *(const float4*)(g + 1024); // o1 stripe
            unsigned* d = &lds[c * CSTRIDE + (f4 >> 3) * ILSTRIDE
                               + ((f4 & 7) << 2)];
            d[0] = pack_h2(a.x, bb.x);
            d[1] = pack_h2(a.y, bb.y);
            d[2] = pack_h2(a.z, bb.z);
            d[3] = pack_h2(a.w, bb.w);
        }
    }
    __syncthreads();

    // ---- compute: j fully unrolled, tables from VGPRs ----
    __half2 acc0 = __float2half2_rn(0.f);       // il0 accumulator (o0,o1)
    __half2 acc1 = __float2half2_rn(0.f);       // il1 accumulator
    #pragma unroll
    for (int j = 0; j < IN_Z; ++j) {
        const unsigned u  = ztab[j];
        const unsigned lo = u & 0xFFFFu;
        const __half2 wz  = u2h(lo | (lo << 16));
        const int     zo  = (int)(u >> 16) + j;
        {
            const int base = xo0 + zo;
            const __half2 q0 = u2h(lds[base]);
            const __half2 q1 = u2h(lds[base + CSTRIDE]);          // read2
            const __half2 v0 = u2h(lds[base + XSTR_A]);
            const __half2 v1 = u2h(lds[base + XSTR_A + CSTRIDE]); // read2
            const __half2 zlo = __hfma2(wz, __hsub2(q1, q0), q0);
            const __half2 zhi = __hfma2(wz, __hsub2(v1, v0), v0);
            acc0 = __hadd2(acc0, __hfma2(wx0, __hsub2(zhi, zlo), zlo));
        }
        {
            const int base = xo1 + zo;
            const __half2 q0 = u2h(lds[base]);
            const __half2 q1 = u2h(lds[base + CSTRIDE]);
            const __half2 v0 = u2h(lds[base + XSTR_A]);
            const __half2 v1 = u2h(lds[base + XSTR_A + CSTRIDE]);
            const __half2 zlo = __hfma2(wz, __hsub2(q1, q0), q0);
            const __half2 zhi = __hfma2(wz, __hsub2(v1, v0), v0);
            acc1 = __hadd2(acc1, __hfma2(wx1, __hsub2(zhi, zlo), zlo));
        }
    }

    // f32 combine of the two per-il half2 partial sums
    const float accx = __low2float(acc0)  + __low2float(acc1);
    const float accy = __high2float(acc0) + __high2float(acc1);

    atomicAdd(&out[o0 * BATCH + b],       accx);
    atomicAdd(&out[(o0 + 1) * BATCH + b], accy);
}

extern "C" void kernel_launch(void* const* d_in, const int* in_sizes, int n_in,
                              void* d_out, int out_size, void* d_ws, size_t ws_size,
                              hipStream_t stream) {
    const float* x       = (const float*)d_in[0];   // (32, 512)
    const float* z       = (const float*)d_in[1];   // (32, 512)
    const float* P       = (const float*)d_in[2];   // (17,17,64,32,32)
    const float* borders = (const float*)d_in[3];   // (17,)
    const float* inv_len = (const float*)d_in[4];   // (16,)
    float* out = (float*)d_out;                     // (64, 512) = 32768

    hipMemsetAsync(out, 0, OUT_DIM * BATCH * sizeof(float), stream);
    bf2d_fused<<<dim3(32 * 8), dim3(1024), 0, stream>>>(
        x, z, borders, inv_len, P, out);
}